// Round 1
// baseline (341.375 us; speedup 1.0000x reference)
//
#include <hip/hip_runtime.h>
#include <hip/hip_bf16.h>

// Conv2DAttentionBlock: B=16, C=128, HW=1024, 4 heads x d=128 attention + 1x1 convs.
// All GEMM-shaped stages in bf16 MFMA (16x16x32), fp32 accumulate.
// Workspace layout (needs 71,827,456 bytes):
//   wqkv  bf16[1536][128]           @ 0
//   wtb   bf16[128][512]            @ 393216
//   xt    bf16[16][1024][128]       @ 524288      (x transposed, n-major)
//   Qt    bf16[16][4][1024][128]    @ 4718592     (n-major)
//   Kt    bf16[16][4][1024][128]    @ 21495808    (m-major)
//   Vd    bf16[16][4][128][1024]    @ 38273024    (d-major)
//   Oscr  bf16[16][1024][512]       @ 55050240    (scrambled-transposed attn out)

#define NB 16
#define CD 128
#define HWN 1024
#define NH 4

typedef __attribute__((ext_vector_type(8))) short bf16x8;
typedef __attribute__((ext_vector_type(4))) short bf16x4;
typedef __attribute__((ext_vector_type(4))) float f32x4;

static __device__ __forceinline__ short f2bf(float f) {
  union { float f; unsigned u; } v; v.f = f;
  unsigned r = v.u + 0x7fffu + ((v.u >> 16) & 1u);  // RNE
  return (short)(r >> 16);
}

// ---- weights: fp32 -> bf16 (Wq,Wk,Wv concat rows; Wt as-is) -------------
__global__ void cvt_weights(const float* __restrict__ Wq, const float* __restrict__ Wk,
                            const float* __restrict__ Wv, const float* __restrict__ Wt,
                            short* __restrict__ wqkv, short* __restrict__ wtb) {
  int i = blockIdx.x * 256 + threadIdx.x;  // grid covers exactly 65536
  wqkv[i]          = f2bf(Wq[i]);
  wqkv[i + 65536]  = f2bf(Wk[i]);
  wqkv[i + 131072] = f2bf(Wv[i]);
  wtb[i]           = f2bf(Wt[i]);
}

// ---- x[b][c][n] fp32 -> xt[b][n][c] bf16 (LDS tile transpose) -----------
__global__ void cvt_transpose_x(const float* __restrict__ x, short* __restrict__ xt) {
  __shared__ short tile[32][33];
  int b = blockIdx.z, c0 = blockIdx.y * 32, n0 = blockIdx.x * 32;
  int tx = threadIdx.x & 31, ty = threadIdx.x >> 5;  // 32x8
  const float* xp = x + ((size_t)b * CD + c0) * HWN + n0;
  for (int k = 0; k < 4; ++k)
    tile[ty + 8 * k][tx] = f2bf(xp[(size_t)(ty + 8 * k) * HWN + tx]);
  __syncthreads();
  short* xo = xt + ((size_t)b * HWN + n0) * CD + c0;
  for (int k = 0; k < 4; ++k)
    xo[(size_t)(ty + 8 * k) * CD + tx] = tile[tx][ty + 8 * k];
}

// ---- QKV: Y[o][n] = sum_c Wqkv[o][c] * x[c][n]; scatter to Qt/Kt/Vd -----
// MFMA: i=o, j=n, k=c. Wave computes 16o x 128n, K=128.
__launch_bounds__(256)
__global__ void qkv_gemm(const short* __restrict__ wqkv, const short* __restrict__ xt,
                         const float* __restrict__ bv,
                         short* __restrict__ Qt, short* __restrict__ Kt,
                         short* __restrict__ Vd) {
  int b = blockIdx.z;
  int wave = threadIdx.x >> 6, lane = threadIdx.x & 63;
  int l15 = lane & 15, l4 = lane >> 4;
  int o0 = blockIdx.y * 64 + wave * 16;   // gridDim.y = 24
  int n0 = blockIdx.x * 128;              // gridDim.x = 8

  bf16x8 afrag[4];
  for (int kt = 0; kt < 4; ++kt)
    afrag[kt] = *(const bf16x8*)(wqkv + (size_t)(o0 + l15) * CD + kt * 32 + l4 * 8);

  f32x4 acc[8];
  for (int jt = 0; jt < 8; ++jt) acc[jt] = (f32x4){0.f, 0.f, 0.f, 0.f};

  const short* xb = xt + (size_t)b * HWN * CD;
  for (int jt = 0; jt < 8; ++jt) {
    int n = n0 + jt * 16 + l15;
    for (int kt = 0; kt < 4; ++kt) {
      bf16x8 bfrag = *(const bf16x8*)(xb + (size_t)n * CD + kt * 32 + l4 * 8);
      acc[jt] = __builtin_amdgcn_mfma_f32_16x16x32_bf16(afrag[kt], bfrag, acc[jt], 0, 0, 0);
    }
  }

  if (o0 < 1024) {  // Q or K -> [b][h][n][d], 4 consecutive d per lane -> 8B store
    short* dst = (o0 < 512) ? Qt : Kt;
    int oo = (o0 < 512) ? o0 : o0 - 512;
    int h = oo >> 7, d0 = (oo & 127) + l4 * 4;
    for (int jt = 0; jt < 8; ++jt) {
      int n = n0 + jt * 16 + l15;
      bf16x4 v4;
      for (int r = 0; r < 4; ++r) v4[r] = f2bf(acc[jt][r]);
      *(bf16x4*)(dst + (((size_t)b * NH + h) * HWN + n) * CD + d0) = v4;
    }
  } else {          // V -> [b][h][d][m] (+bv), scattered 2B stores
    int oo = o0 - 1024;
    int h = oo >> 7, d0 = (oo & 127) + l4 * 4;
    float bvv[4];
    for (int r = 0; r < 4; ++r) bvv[r] = bv[oo + l4 * 4 + r];
    for (int jt = 0; jt < 8; ++jt) {
      int n = n0 + jt * 16 + l15;
      for (int r = 0; r < 4; ++r)
        Vd[(((size_t)b * NH + h) * CD + d0 + r) * HWN + n] = f2bf(acc[jt][r] + bvv[r]);
    }
  }
}

// ---- flash attention per (b,h): S=1024, D=128 ---------------------------
// Wave owns 16 Q-rows; m-tiles of 32; P staged via per-wave LDS tile.
__launch_bounds__(256)
__global__ void attn(const short* __restrict__ Qt, const short* __restrict__ Kt,
                     const short* __restrict__ Vd, short* __restrict__ Oscr) {
  int b = blockIdx.z, h = blockIdx.y;
  int wave = threadIdx.x >> 6, lane = threadIdx.x & 63;
  int l15 = lane & 15, l4 = lane >> 4;
  int n0 = blockIdx.x * 64 + wave * 16;   // gridDim.x = 16
  size_t bh = (size_t)b * NH + h;
  const short* q = Qt + bh * HWN * CD;
  const short* k = Kt + bh * HWN * CD;
  const short* v = Vd + bh * CD * HWN;

  __shared__ short plds[4][16][32];

  bf16x8 aq[4];
  for (int kt = 0; kt < 4; ++kt)
    aq[kt] = *(const bf16x8*)(q + (size_t)(n0 + l15) * CD + kt * 32 + l4 * 8);

  f32x4 oacc[8];
  for (int jt = 0; jt < 8; ++jt) oacc[jt] = (f32x4){0.f, 0.f, 0.f, 0.f};
  float mi[4], li[4];
  for (int r = 0; r < 4; ++r) { mi[r] = -1e30f; li[r] = 0.f; }

  const float scale = 0.08838834764831845f;  // 1/sqrt(128)

  for (int mt = 0; mt < 32; ++mt) {
    int m0 = mt * 32;
    f32x4 s0 = {0.f, 0.f, 0.f, 0.f}, s1 = {0.f, 0.f, 0.f, 0.f};
    for (int kt = 0; kt < 4; ++kt) {
      bf16x8 bk0 = *(const bf16x8*)(k + (size_t)(m0 + l15) * CD + kt * 32 + l4 * 8);
      bf16x8 bk1 = *(const bf16x8*)(k + (size_t)(m0 + 16 + l15) * CD + kt * 32 + l4 * 8);
      s0 = __builtin_amdgcn_mfma_f32_16x16x32_bf16(aq[kt], bk0, s0, 0, 0, 0);
      s1 = __builtin_amdgcn_mfma_f32_16x16x32_bf16(aq[kt], bk1, s1, 0, 0, 0);
    }
    // online softmax: row i = l4*4+r lives across the 16 lanes sharing l4
    float fac[4];
    for (int r = 0; r < 4; ++r) {
      float a0 = s0[r] * scale, a1 = s1[r] * scale;
      float mx = fmaxf(a0, a1);
      mx = fmaxf(mx, __shfl_xor(mx, 1));
      mx = fmaxf(mx, __shfl_xor(mx, 2));
      mx = fmaxf(mx, __shfl_xor(mx, 4));
      mx = fmaxf(mx, __shfl_xor(mx, 8));
      float nm = fmaxf(mi[r], mx);
      fac[r] = __expf(mi[r] - nm);
      float p0 = __expf(a0 - nm), p1 = __expf(a1 - nm);
      float rs = p0 + p1;
      rs += __shfl_xor(rs, 1);
      rs += __shfl_xor(rs, 2);
      rs += __shfl_xor(rs, 4);
      rs += __shfl_xor(rs, 8);
      li[r] = li[r] * fac[r] + rs;
      mi[r] = nm;
      s0[r] = p0; s1[r] = p1;
    }
    for (int jt = 0; jt < 8; ++jt)
      for (int r = 0; r < 4; ++r) oacc[jt][r] *= fac[r];
    // P (D-layout) -> LDS [16 rows][32 cols], then read back as A fragment
    for (int r = 0; r < 4; ++r) {
      plds[wave][l4 * 4 + r][l15]      = f2bf(s0[r]);
      plds[wave][l4 * 4 + r][16 + l15] = f2bf(s1[r]);
    }
    asm volatile("s_waitcnt lgkmcnt(0)" ::: "memory");  // intra-wave LDS W->R order
    bf16x8 ap = *(const bf16x8*)(&plds[wave][l15][l4 * 8]);
    for (int jt = 0; jt < 8; ++jt) {
      bf16x8 bvf = *(const bf16x8*)(v + (size_t)(jt * 16 + l15) * HWN + m0 + l4 * 8);
      oacc[jt] = __builtin_amdgcn_mfma_f32_16x16x32_bf16(ap, bvf, oacc[jt], 0, 0, 0);
    }
  }

  // epilogue: O[n][d]/l -> Oscr[b][m=(n%8)*128+d][o=h*128+n/8]  (bijective)
  float inv[4];
  for (int r = 0; r < 4; ++r) inv[r] = 1.0f / li[r];
  for (int jt = 0; jt < 8; ++jt) {
    int d = jt * 16 + l15;
    for (int r = 0; r < 4; ++r) {
      int n = n0 + l4 * 4 + r;
      int o = h * CD + (n >> 3);
      int msp = (n & 7) * CD + d;
      Oscr[((size_t)b * HWN + msp) * 512 + o] = f2bf(oacc[jt][r] * inv[r]);
    }
  }
}

// ---- proj: out[b][c][m] = x + bt[c] + sum_o Wt[c][o]*OscrT[m][o] --------
// MFMA: i=m, j=c, k=o. Both operands k-contiguous; float4 output stores.
__launch_bounds__(256)
__global__ void proj_kernel(const short* __restrict__ Oscr, const short* __restrict__ wtb,
                            const float* __restrict__ bt, const float* __restrict__ x,
                            float* __restrict__ out) {
  int b = blockIdx.y;
  int wave = threadIdx.x >> 6, lane = threadIdx.x & 63;
  int l15 = lane & 15, l4 = lane >> 4;
  int m0 = blockIdx.x * 64 + wave * 16;   // gridDim.x = 16

  f32x4 acc[8];
  for (int jt = 0; jt < 8; ++jt) acc[jt] = (f32x4){0.f, 0.f, 0.f, 0.f};

  const short* ob = Oscr + (size_t)b * HWN * 512;
  for (int kt = 0; kt < 16; ++kt) {
    bf16x8 a = *(const bf16x8*)(ob + (size_t)(m0 + l15) * 512 + kt * 32 + l4 * 8);
    for (int jt = 0; jt < 8; ++jt) {
      bf16x8 bw = *(const bf16x8*)(wtb + (size_t)(jt * 16 + l15) * 512 + kt * 32 + l4 * 8);
      acc[jt] = __builtin_amdgcn_mfma_f32_16x16x32_bf16(a, bw, acc[jt], 0, 0, 0);
    }
  }
  for (int jt = 0; jt < 8; ++jt) {
    int c = jt * 16 + l15;
    float btc = bt[c];
    size_t base = ((size_t)b * CD + c) * HWN + m0 + l4 * 4;
    f32x4 xr = *(const f32x4*)(x + base);
    f32x4 o;
    for (int r = 0; r < 4; ++r) o[r] = acc[jt][r] + xr[r] + btc;
    *(f32x4*)(out + base) = o;
  }
}

extern "C" void kernel_launch(void* const* d_in, const int* in_sizes, int n_in,
                              void* d_out, int out_size, void* d_ws, size_t ws_size,
                              hipStream_t stream) {
  const float* x  = (const float*)d_in[0];
  const float* Wq = (const float*)d_in[1];
  const float* Wk = (const float*)d_in[2];
  const float* Wv = (const float*)d_in[3];
  const float* bv = (const float*)d_in[4];
  const float* Wt = (const float*)d_in[5];
  const float* bt = (const float*)d_in[6];
  float* out = (float*)d_out;
  char* ws = (char*)d_ws;

  short* wqkv = (short*)(ws);
  short* wtb  = (short*)(ws + 393216);
  short* xt   = (short*)(ws + 524288);
  short* Qt   = (short*)(ws + 4718592);
  short* Kt   = (short*)(ws + 21495808);
  short* Vd   = (short*)(ws + 38273024);
  short* Oscr = (short*)(ws + 55050240);  // total 71827456 bytes

  hipLaunchKernelGGL(cvt_weights, dim3(256), dim3(256), 0, stream, Wq, Wk, Wv, Wt, wqkv, wtb);
  hipLaunchKernelGGL(cvt_transpose_x, dim3(32, 4, 16), dim3(256), 0, stream, x, xt);
  hipLaunchKernelGGL(qkv_gemm, dim3(8, 24, 16), dim3(256), 0, stream, wqkv, xt, bv, Qt, Kt, Vd);
  hipLaunchKernelGGL(attn, dim3(16, 4, 16), dim3(256), 0, stream, Qt, Kt, Vd, Oscr);
  hipLaunchKernelGGL(proj_kernel, dim3(16, 16), dim3(256), 0, stream, Oscr, wtb, bt, x, out);
}